// Round 4
// baseline (257.117 us; speedup 1.0000x reference)
//
#include <hip/hip_runtime.h>
#include <math.h>

typedef unsigned long long ull;
typedef unsigned short ushort_t;
typedef __attribute__((ext_vector_type(8))) short bf16x8;
typedef __attribute__((ext_vector_type(4))) float f32x4;

#define PPB   16384
#define NB    4
#define TOPK  4096
#define NPTS  65536
#define NBUCK 16384

// workspace layout (bytes)
#define PF_OFF    0u          // N*256 bf16 = 32 MB
#define SRAW_OFF  33554432u   // N f32
#define SC_OFF    33816576u   // N f32
#define ST_OFF    34078720u   // 64 words stats
#define HIST_OFF  34078976u   // 4*16384 u32 = 256 KB
#define CNT2_OFF  34341120u   // 4*16384 u32
#define SUF_OFF   34603264u   // 4*16384 u32
#define CAND_OFF  34865408u   // 4*16384 u64 = 512 KB
#define FIDX_OFF  35389696u   // 16384 i32
#define W2SH_OFF  35455232u   // 256*256 bf16 chunk-swizzled image (hi)
#define W2SL_OFF  35586304u   // (lo)
#define WP1H_OFF  35717376u   // wp1^T image (hi)
#define WP1L_OFF  35848448u   // (lo)   end 35979520

// stats word indices
#define SI_SUMS  0
#define SI_SUMS2 1
#define SI_CNT0  4   // ..7  per-batch candidate totals
#define SI_EALL  8   // ..11 per-batch sum exp (all, shift C=5)
#define SI_ESEL  12  // ..15 per-batch sum exp (selected)
#define SI_BCUT  20  // ..23

__device__ __forceinline__ unsigned short f2bf(float f) {
  unsigned u = __float_as_uint(f);
  unsigned r = 0x7FFFu + ((u >> 16) & 1u);   // RTNE
  return (unsigned short)((u + r) >> 16);
}
__device__ __forceinline__ float bf2f(unsigned short h) {
  return __uint_as_float((unsigned)h << 16);
}
// async global->LDS, 16B per lane; LDS dest = wave-uniform base + lane*16
__device__ __forceinline__ void glds16(const unsigned short* g, short* l) {
  __builtin_amdgcn_global_load_lds(
      (const __attribute__((address_space(1))) unsigned int*)g,
      (__attribute__((address_space(3))) unsigned int*)l, 16, 0, 0);
}

// ---------------- prep: images (coalesced) + workspace zeroing ----------------
// blocks 0-7: w2 chunks; 8-15: wp1 chunks; 16-23: zero stats+hist+cnt2
__global__ __launch_bounds__(256) void k_prep(
    const float* __restrict__ w2, const float* __restrict__ wp1,
    unsigned short* __restrict__ w2h, unsigned short* __restrict__ w2l,
    unsigned short* __restrict__ p1h, unsigned short* __restrict__ p1l,
    uint4* __restrict__ zero_base)
{
  const int t = threadIdx.x, bx = blockIdx.x;
  if (bx >= 16) {
    const int z = bx - 16;
    const unsigned nz = (256u + 2u * NB * NBUCK * 4u) / 16u;  // uint4 count
    uint4 zv = {0u, 0u, 0u, 0u};
    for (unsigned i = z * 256 + t; i < nz; i += 2048) zero_base[i] = zv;
    return;
  }
  __shared__ unsigned short lh[8192], ll[8192];
  const int c = bx & 7;
  const float* src = (bx >= 8) ? wp1 : w2;
  unsigned short* dh = (bx >= 8) ? p1h : w2h;
  unsigned short* dl = (bx >= 8) ? p1l : w2l;
  const int sw = (t >> 1) & 3;
#pragma unroll
  for (int kk = 0; kk < 32; ++kk) {
    float v = src[(c * 32 + kk) * 256 + t];      // coalesced 256-wide
    unsigned short h = f2bf(v);
    int q = kk >> 3, kof = kk & 7;
    int off = t * 32 + ((q ^ sw) << 3) + kof;
    lh[off] = h;
    ll[off] = f2bf(v - bf2f(h));
  }
  __syncthreads();
#pragma unroll
  for (int u = 0; u < 4; ++u) {
    ((uint4*)&dh[c * 8192])[u * 256 + t] = ((const uint4*)lh)[u * 256 + t];
    ((uint4*)&dl[c * 8192])[u * 256 + t] = ((const uint4*)ll)[u * 256 + t];
  }
}

// ---------------- K1: point MLP, M=256/block, full dbuf, 1 barrier/chunk ----------------
__global__ __launch_bounds__(256, 1) void k_mlp(
    const float4* __restrict__ pts4, const float* __restrict__ w1,
    const float* __restrict__ b1,
    const unsigned short* __restrict__ w2h, const unsigned short* __restrict__ w2l,
    const float* __restrict__ b2, const float* __restrict__ wsv,
    const float* __restrict__ bs,
    uint4* __restrict__ pf_u4, float* __restrict__ s_raw, float* stats_f)
{
  __shared__ __align__(16) short a_s[2][16384];   // [buf][hi 8192 | lo 8192] 64 KB
  __shared__ __align__(16) short b_s[2][16384];   // 64 KB
  __shared__ float w1_l[1024], b1_l[256], pts_l[1024];
  __shared__ float red[8];

  const int t = threadIdx.x;
  const int m0 = blockIdx.x * 256;
  const int wv = t >> 6, lane = t & 63, g = lane >> 4, c0 = lane & 15;
  const int kp = t & 15, rg = t >> 4;

#pragma unroll
  for (int i = 0; i < 4; ++i) w1_l[i * 256 + t] = w1[i * 256 + t];
  b1_l[t] = b1[t];
  ((float4*)pts_l)[t] = pts4[m0 + t];

  f32x4 acc[16][4];
#pragma unroll
  for (int i = 0; i < 16; ++i)
#pragma unroll
    for (int j = 0; j < 4; ++j) acc[i][j] = (f32x4){0.f, 0.f, 0.f, 0.f};
  __syncthreads();

  float4 ptr_[16];
#pragma unroll
  for (int r = 0; r < 16; ++r) ptr_[r] = ((const float4*)pts_l)[rg * 16 + r];

  const int qa = kp >> 2, kof = (2 * kp) & 7;

  // ---- stage helpers inlined via lambdas ----
  auto stageB = [&](int cc, int bb) {
    const unsigned short* gh = w2h + cc * 8192;
    const unsigned short* gl = w2l + cc * 8192;
    short* bh = &b_s[bb][0];
    short* bl = &b_s[bb][8192];
#pragma unroll
    for (int j = 0; j < 4; ++j) {
      glds16(gh + (j * 256 + t) * 8, bh + (j * 256 + wv * 64) * 8);
      glds16(gl + (j * 256 + t) * 8, bl + (j * 256 + wv * 64) * 8);
    }
  };
  auto computeA = [&](int cc, int bb) {
    int kg = cc * 32 + 2 * kp;
    float wa0 = w1_l[kg],       wa1 = w1_l[256 + kg];
    float wa2 = w1_l[512 + kg], wa3 = w1_l[768 + kg];
    float wb0 = w1_l[kg + 1],       wb1 = w1_l[256 + kg + 1];
    float wb2 = w1_l[512 + kg + 1], wb3 = w1_l[768 + kg + 1];
    float ba = b1_l[kg], bb_ = b1_l[kg + 1];
    short* ah = &a_s[bb][0];
    short* al = &a_s[bb][8192];
#pragma unroll
    for (int r = 0; r < 16; ++r) {
      int m = rg * 16 + r;
      float4 pv = ptr_[r];
      float h0 = fmaf(pv.w, wa3, fmaf(pv.z, wa2, fmaf(pv.y, wa1, fmaf(pv.x, wa0, ba))));
      float h1 = fmaf(pv.w, wb3, fmaf(pv.z, wb2, fmaf(pv.y, wb1, fmaf(pv.x, wb0, bb_))));
      h0 = fmaxf(h0, 0.f); h1 = fmaxf(h1, 0.f);
      unsigned short h0h = f2bf(h0), h1h = f2bf(h1);
      unsigned short l0h = f2bf(h0 - bf2f(h0h)), l1h = f2bf(h1 - bf2f(h1h));
      int base = m * 32 + ((qa ^ ((m >> 1) & 3)) << 3) + kof;
      *(unsigned*)&ah[base] = (unsigned)h0h | ((unsigned)h1h << 16);
      *(unsigned*)&al[base] = (unsigned)l0h | ((unsigned)l1h << 16);
    }
  };

  stageB(0, 0);
  computeA(0, 0);

  for (int c = 0; c < 8; ++c) {
    __syncthreads();                 // chunk c staged (glds drained) + A ready
    const int nc = (c + 1) & 7, nb = (c + 1) & 1, cb = c & 1;
    stageB(nc, nb);                  // async prefetch overlaps MFMA below
    const short* bh = &b_s[cb][0];
    const short* bl = &b_s[cb][8192];
    const short* ah = &a_s[cb][0];
    const short* al = &a_s[cb][8192];
    bf16x8 bhf[4], blf[4];
#pragma unroll
    for (int nt = 0; nt < 4; ++nt) {
      int n = wv * 64 + nt * 16 + c0;
      int off = n * 32 + ((g ^ ((n >> 1) & 3)) << 3);
      bhf[nt] = *(const bf16x8*)&bh[off];
      blf[nt] = *(const bf16x8*)&bl[off];
    }
#pragma unroll
    for (int mt = 0; mt < 16; ++mt) {
      int m = mt * 16 + c0;
      int off = m * 32 + ((g ^ ((m >> 1) & 3)) << 3);
      bf16x8 af = *(const bf16x8*)&ah[off];
      bf16x8 alf = *(const bf16x8*)&al[off];
#pragma unroll
      for (int nt = 0; nt < 4; ++nt) {
        acc[mt][nt] = __builtin_amdgcn_mfma_f32_16x16x32_bf16(af, bhf[nt], acc[mt][nt], 0, 0, 0);
        acc[mt][nt] = __builtin_amdgcn_mfma_f32_16x16x32_bf16(alf, bhf[nt], acc[mt][nt], 0, 0, 0);
        acc[mt][nt] = __builtin_amdgcn_mfma_f32_16x16x32_bf16(af, blf[nt], acc[mt][nt], 0, 0, 0);
      }
    }
    computeA(nc, nb);                // VALU overlaps MFMA (writes other buffer)
  }
  __syncthreads();

  // ---- epilogue: relu+b2 -> pf bf16 (4 passes of 64 rows), s row-sums ----
  unsigned short* pstage = (unsigned short*)&b_s[0][0];  // 32 KB
  float* spart = (float*)&a_s[0][0];                     // 4 KB
  float wsr[4], b2v[4];
#pragma unroll
  for (int nt = 0; nt < 4; ++nt) {
    int col = wv * 64 + nt * 16 + c0;
    wsr[nt] = wsv[col]; b2v[nt] = b2[col];
  }
  for (int p = 0; p < 4; ++p) {
#pragma unroll
    for (int mi = 0; mi < 4; ++mi) {
      int mt = p * 4 + mi;
      float srow[4] = {0.f, 0.f, 0.f, 0.f};
#pragma unroll
      for (int nt = 0; nt < 4; ++nt) {
        f32x4 z = acc[mt][nt];
#pragma unroll
        for (int r = 0; r < 4; ++r) {
          float pp = fmaxf(z[r] + b2v[nt], 0.f);
          srow[r] = fmaf(pp, wsr[nt], srow[r]);
          pstage[(mi * 16 + g * 4 + r) * 256 + wv * 64 + nt * 16 + c0] = f2bf(pp);
        }
      }
#pragma unroll
      for (int r = 0; r < 4; ++r) {
#pragma unroll
        for (int off = 1; off <= 8; off <<= 1) srow[r] += __shfl_xor(srow[r], off);
        if (c0 == 0) spart[(mt * 16 + g * 4 + r) * 4 + wv] = srow[r];
      }
    }
    __syncthreads();
#pragma unroll
    for (int u = 0; u < 8; ++u) {
      int jj = u * 256 + t, row = jj >> 5, c4 = jj & 31;
      pf_u4[(size_t)(m0 + p * 64 + row) * 32 + c4] = ((const uint4*)pstage)[jj];
    }
    __syncthreads();
  }
  {
    float s = bs[0] + spart[t * 4] + spart[t * 4 + 1] + spart[t * 4 + 2] + spart[t * 4 + 3];
    s_raw[m0 + t] = s;
    float s2 = s * s;
#pragma unroll
    for (int off = 32; off >= 1; off >>= 1) {
      s += __shfl_down(s, off);
      s2 += __shfl_down(s2, off);
    }
    if (lane == 0) { red[wv * 2] = s; red[wv * 2 + 1] = s2; }
    __syncthreads();
    if (t == 0) {
      atomicAdd(&stats_f[SI_SUMS], red[0] + red[2] + red[4] + red[6]);
      atomicAdd(&stats_f[SI_SUMS2], red[1] + red[3] + red[5] + red[7]);
    }
  }
}

// ---------------- K3: scores (BN fused) + fine histogram + EALL ----------------
__global__ __launch_bounds__(256) void k_scores(
    const float* __restrict__ s_raw, const float* stats_f,
    const float* __restrict__ gamma, const float* __restrict__ beta,
    float* __restrict__ scores, unsigned* __restrict__ hist, float* stats_fo)
{
  int i = blockIdx.x * 256 + threadIdx.x;
  int batch = i >> 14;
  float mu = stats_f[SI_SUMS] * (1.f / 65536.f);
  float ex2 = stats_f[SI_SUMS2] * (1.f / 65536.f);
  float istd = 1.f / sqrtf(ex2 - mu * mu + 1e-5f);
  float sc = fmaxf((s_raw[i] - mu) * istd * gamma[0] + beta[0], 0.f);
  scores[i] = sc;
  unsigned bucket = __float_as_uint(sc) >> 17;
  if (bucket > NBUCK - 1u) bucket = NBUCK - 1u;
  if (bucket >= 1u) atomicAdd(&hist[batch * NBUCK + bucket], 1u);
  float e = expf((sc - 5.f) * 10.f);
#pragma unroll
  for (int off = 32; off >= 1; off >>= 1) e += __shfl_down(e, off);
  if ((threadIdx.x & 63) == 0) atomicAdd(&stats_fo[SI_EALL + batch], e);
}

// ---------------- K4: per-batch suffix scan (coalesced via LDS) ----------------
__global__ __launch_bounds__(1024) void k_cutoff(
    const unsigned* __restrict__ hist, unsigned* __restrict__ suf, unsigned* stats_u)
{
  __shared__ unsigned lh[NBUCK];      // 64 KB
  __shared__ unsigned wsum[16], wsuf[16];
  const int batch = blockIdx.x, t = threadIdx.x;
  const int base = batch * NBUCK;
  const int lane = t & 63, w = t >> 6;
#pragma unroll
  for (int j = 0; j < 16; ++j) lh[j * 1024 + t] = hist[base + j * 1024 + t];
  __syncthreads();
  unsigned hl[16]; unsigned ct = 0;
#pragma unroll
  for (int i = 0; i < 16; ++i) { hl[i] = lh[t * 16 + i]; ct += hl[i]; }
  unsigned x = ct;
#pragma unroll
  for (int off = 1; off <= 32; off <<= 1) {
    unsigned v = __shfl_down(x, off);
    if (lane + off < 64) x += v;
  }
  if (lane == 0) wsum[w] = x;
  __syncthreads();
  if (t < 16) {
    unsigned s = 0;
    for (int j = t + 1; j < 16; ++j) s += wsum[j];
    wsuf[t] = s;
  }
  __syncthreads();
  unsigned run = wsuf[w] + (x - ct);
  for (int i = 15; i >= 0; --i) {
    int b = t * 16 + i;
    unsigned h = hl[i];
    lh[b] = run;
    if (b >= 1 && run < TOPK && run + h >= TOPK) {
      stats_u[SI_BCUT + batch] = (unsigned)b;
      stats_u[SI_CNT0 + batch] = run + h;
    }
    run += h;
  }
  if (t == 0 && run < TOPK) {
    stats_u[SI_BCUT + batch] = 0u;
    stats_u[SI_CNT0 + batch] = PPB;
  }
  __syncthreads();
#pragma unroll
  for (int j = 0; j < 16; ++j) suf[base + j * 1024 + t] = lh[j * 1024 + t];
}

// ---------------- K5: scatter candidates into per-bucket segments ----------------
__global__ __launch_bounds__(256) void k_scatter(
    const float* __restrict__ scores, const unsigned* __restrict__ suf,
    unsigned* __restrict__ cnt2, const unsigned* stats_u, ull* __restrict__ cand)
{
  int i = blockIdx.x * 256 + threadIdx.x;
  int batch = i >> 14;
  unsigned bits = __float_as_uint(scores[i]);
  unsigned bucket = bits >> 17;
  if (bucket > NBUCK - 1u) bucket = NBUCK - 1u;
  unsigned c = stats_u[SI_BCUT + batch];
  if (bucket >= c) {
    unsigned slot = atomicAdd(&cnt2[batch * NBUCK + bucket], 1u);
    unsigned pos = suf[batch * NBUCK + bucket] + slot;
    cand[batch * PPB + pos] = ((ull)bits << 32) | (ull)(~(unsigned)i);
  }
}

// ---------------- K6: rank within segment -> flat_idx + ESEL ----------------
__global__ __launch_bounds__(1024) void k_rank(
    const ull* __restrict__ cand, const unsigned* __restrict__ suf,
    const unsigned* __restrict__ hist, const unsigned* stats_u, float* stats_f,
    int* __restrict__ flat_idx)
{
  int tid = blockIdx.x * 1024 + threadIdx.x;
  int batch = tid >> 14;
  int pos = tid & 16383;
  unsigned tot = stats_u[SI_CNT0 + batch];
  float esel = 0.f;
  if ((unsigned)pos < tot) {
    ull key = cand[batch * PPB + pos];
    unsigned bits = (unsigned)(key >> 32);
    unsigned bucket = bits >> 17;
    unsigned s0 = suf[batch * NBUCK + bucket];
    unsigned s1 = (bucket >= 1u) ? s0 + hist[batch * NBUCK + bucket] : tot;
    unsigned rank = s0;
    const ull* seg = &cand[batch * PPB];
    for (unsigned p = s0; p < s1; ++p) rank += (seg[p] > key);
    if (rank < TOPK) {
      flat_idx[batch * TOPK + rank] = (int)(~(unsigned)key);
      esel = expf((__uint_as_float(bits) - 5.f) * 10.f);
    }
  }
#pragma unroll
  for (int off = 32; off >= 1; off >>= 1) esel += __shfl_down(esel, off);
  if ((threadIdx.x & 63) == 0) atomicAdd(&stats_f[SI_ESEL + batch], esel);
}

// ---------------- K7: processor MLP, 2-chain split-bf16 MFMA ----------------
__global__ __launch_bounds__(256) void k_proc(
    const uint4* __restrict__ pf_u4, const float* __restrict__ scores,
    const float* stats_f, const int* __restrict__ flat_idx,
    const unsigned short* __restrict__ p1h, const unsigned short* __restrict__ p1l,
    const float* __restrict__ bp1,
    const float4* __restrict__ wp2_4, const float* __restrict__ bp2,
    float4* __restrict__ out4)
{
  __shared__ __align__(16) short a_s[2048];           // 4 KB
  __shared__ __align__(16) short smem_b[2 * 8192];    // 32 KB
  short* b_hi = smem_b; short* b_lo = smem_b + 8192;
  __shared__ int idx_t[64];
  __shared__ float sw_t[64];
  __shared__ float opart[4 * 64 * 4];
  const int t = threadIdx.x;
  const int m0 = blockIdx.x * 64;
  const int b = m0 >> 12;
  const int wv = t >> 6, lane = t & 63, g = lane >> 4, c0 = lane & 15;

  if (t < 64) {
    int idx = flat_idx[m0 + t];
    float Z = stats_f[SI_EALL] + stats_f[SI_EALL + 1] +
              stats_f[SI_EALL + 2] + stats_f[SI_EALL + 3];
    float E = expf((scores[idx] - 5.f) * 10.f);
    idx_t[t] = idx;
    sw_t[t] = E / (stats_f[SI_ESEL + b] + 1e-8f * Z);
  }
  f32x4 acc[4][4];
#pragma unroll
  for (int i = 0; i < 4; ++i)
#pragma unroll
    for (int j = 0; j < 4; ++j) acc[i][j] = (f32x4){0.f, 0.f, 0.f, 0.f};
  __syncthreads();

  const int mq = t >> 2, qa = t & 3;
  for (int kc8 = 0; kc8 < 8; ++kc8) {
#pragma unroll
    for (int j = 0; j < 4; ++j) {
      glds16(p1h + kc8 * 8192 + (j * 256 + t) * 8, b_hi + (j * 256 + wv * 64) * 8);
      glds16(p1l + kc8 * 8192 + (j * 256 + t) * 8, b_lo + (j * 256 + wv * 64) * 8);
    }
    {
      uint4 v = pf_u4[(size_t)idx_t[mq] * 32 + kc8 * 4 + qa];
      *(uint4*)&a_s[mq * 32 + ((qa ^ ((mq >> 1) & 3)) << 3)] = v;
    }
    __syncthreads();
    bf16x8 bhf[4], blf[4];
#pragma unroll
    for (int nt = 0; nt < 4; ++nt) {
      int n = wv * 64 + nt * 16 + c0;
      int off = n * 32 + ((g ^ ((n >> 1) & 3)) << 3);
      bhf[nt] = *(const bf16x8*)&b_hi[off];
      blf[nt] = *(const bf16x8*)&b_lo[off];
    }
#pragma unroll
    for (int mt = 0; mt < 4; ++mt) {
      int m = mt * 16 + c0;
      bf16x8 af = *(const bf16x8*)&a_s[m * 32 + ((g ^ ((m >> 1) & 3)) << 3)];
#pragma unroll
      for (int nt = 0; nt < 4; ++nt) {
        acc[mt][nt] = __builtin_amdgcn_mfma_f32_16x16x32_bf16(af, bhf[nt], acc[mt][nt], 0, 0, 0);
        acc[mt][nt] = __builtin_amdgcn_mfma_f32_16x16x32_bf16(af, blf[nt], acc[mt][nt], 0, 0, 0);
      }
    }
    __syncthreads();
  }

  float4 wq[4]; float bp1v[4];
#pragma unroll
  for (int nt = 0; nt < 4; ++nt) {
    int n = wv * 64 + nt * 16 + c0;
    wq[nt] = wp2_4[n]; bp1v[nt] = bp1[n];
  }
#pragma unroll
  for (int mt = 0; mt < 4; ++mt) {
#pragma unroll
    for (int r = 0; r < 4; ++r) {
      float4 o = {0.f, 0.f, 0.f, 0.f};
#pragma unroll
      for (int nt = 0; nt < 4; ++nt) {
        float y = fmaxf(acc[mt][nt][r] + bp1v[nt], 0.f);
        o.x = fmaf(y, wq[nt].x, o.x); o.y = fmaf(y, wq[nt].y, o.y);
        o.z = fmaf(y, wq[nt].z, o.z); o.w = fmaf(y, wq[nt].w, o.w);
      }
#pragma unroll
      for (int off = 1; off <= 8; off <<= 1) {
        o.x += __shfl_xor(o.x, off); o.y += __shfl_xor(o.y, off);
        o.z += __shfl_xor(o.z, off); o.w += __shfl_xor(o.w, off);
      }
      if (c0 == 0) *(float4*)&opart[(wv * 64 + mt * 16 + g * 4 + r) * 4] = o;
    }
  }
  __syncthreads();
  if (t < 64) {
    float4 bp2v = *(const float4*)bp2;
    float4 s0 = *(float4*)&opart[t * 4];
    float4 s1 = *(float4*)&opart[(64 + t) * 4];
    float4 s2 = *(float4*)&opart[(128 + t) * 4];
    float4 s3 = *(float4*)&opart[(192 + t) * 4];
    float sw = sw_t[t];
    float4 r;
    r.x = fmaf(s0.x + s1.x + s2.x + s3.x, sw, bp2v.x);
    r.y = fmaf(s0.y + s1.y + s2.y + s3.y, sw, bp2v.y);
    r.z = fmaf(s0.z + s1.z + s2.z + s3.z, sw, bp2v.z);
    r.w = fmaf(s0.w + s1.w + s2.w + s3.w, sw, bp2v.w);
    out4[m0 + t] = r;
  }
}

extern "C" void kernel_launch(void* const* d_in, const int* in_sizes, int n_in,
                              void* d_out, int out_size, void* d_ws, size_t ws_size,
                              hipStream_t stream) {
  const float* pts   = (const float*)d_in[0];
  const float* w1    = (const float*)d_in[1];
  const float* b1    = (const float*)d_in[2];
  const float* w2    = (const float*)d_in[3];
  const float* b2    = (const float*)d_in[4];
  const float* wsv   = (const float*)d_in[5];
  const float* bs    = (const float*)d_in[6];
  const float* gamma = (const float*)d_in[7];
  const float* beta  = (const float*)d_in[8];
  const float* wp1   = (const float*)d_in[9];
  const float* bp1   = (const float*)d_in[10];
  const float* wp2   = (const float*)d_in[11];
  const float* bp2   = (const float*)d_in[12];

  char* wsb = (char*)d_ws;
  uint4*    pf      = (uint4*)(wsb + PF_OFF);
  float*    s_raw   = (float*)(wsb + SRAW_OFF);
  float*    scores  = (float*)(wsb + SC_OFF);
  float*    stats_f = (float*)(wsb + ST_OFF);
  unsigned* stats_u = (unsigned*)(wsb + ST_OFF);
  unsigned* hist    = (unsigned*)(wsb + HIST_OFF);
  unsigned* cnt2    = (unsigned*)(wsb + CNT2_OFF);
  unsigned* suf     = (unsigned*)(wsb + SUF_OFF);
  ull*      cand    = (ull*)(wsb + CAND_OFF);
  int*      flat_i  = (int*)(wsb + FIDX_OFF);
  unsigned short* w2h = (unsigned short*)(wsb + W2SH_OFF);
  unsigned short* w2l = (unsigned short*)(wsb + W2SL_OFF);
  unsigned short* p1h = (unsigned short*)(wsb + WP1H_OFF);
  unsigned short* p1l = (unsigned short*)(wsb + WP1L_OFF);

  hipLaunchKernelGGL(k_prep, dim3(24), dim3(256), 0, stream,
                     w2, wp1, w2h, w2l, p1h, p1l, (uint4*)(wsb + ST_OFF));
  hipLaunchKernelGGL(k_mlp, dim3(256), dim3(256), 0, stream,
                     (const float4*)pts, w1, b1, w2h, w2l, b2, wsv, bs,
                     pf, s_raw, stats_f);
  hipLaunchKernelGGL(k_scores, dim3(256), dim3(256), 0, stream,
                     s_raw, stats_f, gamma, beta, scores, hist, stats_f);
  hipLaunchKernelGGL(k_cutoff, dim3(NB), dim3(1024), 0, stream, hist, suf, stats_u);
  hipLaunchKernelGGL(k_scatter, dim3(256), dim3(256), 0, stream,
                     scores, suf, cnt2, stats_u, cand);
  hipLaunchKernelGGL(k_rank, dim3(64), dim3(1024), 0, stream,
                     cand, suf, hist, stats_u, stats_f, flat_i);
  hipLaunchKernelGGL(k_proc, dim3(256), dim3(256), 0, stream,
                     pf, scores, stats_f, flat_i, p1h, p1l, bp1,
                     (const float4*)wp2, bp2, (float4*)d_out);
}

// Round 5
// 191.695 us; speedup vs baseline: 1.3413x; 1.3413x over previous
//
#include <hip/hip_runtime.h>
#include <math.h>

typedef unsigned long long ull;
typedef __attribute__((ext_vector_type(8))) short bf16x8;
typedef __attribute__((ext_vector_type(4))) float f32x4;

#define PPB   16384
#define NB    4
#define TOPK  4096
#define NPTS  65536
#define NBUCK 16384

// workspace layout (bytes)
#define PF_OFF    0u          // N*256 bf16 = 32 MB
#define SRAW_OFF  33554432u   // N f32
#define SC_OFF    33816576u   // N f32
#define ST_OFF    34078720u   // 64 words stats
#define HIST_OFF  34078976u   // 4*16384 u32 = 256 KB
#define SUF_OFF   34603264u   // 4*16384 u32
#define CAND_OFF  34865408u   // 4*16384 u64 = 512 KB
#define FIDX_OFF  35389696u   // 16384 i32
#define W2SH_OFF  35455232u   // 256*256 bf16 chunk-swizzled image (hi)
#define W2SL_OFF  35586304u   // (lo)
#define WP1H_OFF  35717376u   // wp1^T image (hi)
#define WP1L_OFF  35848448u   // (lo)   end 35979520

// stats word indices
#define SI_SUMS  0
#define SI_SUMS2 1
#define SI_CNT0  4   // ..7  per-batch candidate totals
#define SI_EALL  8   // ..11 per-batch sum exp (all, shift C=5)
#define SI_ESEL  12  // ..15 per-batch sum exp (selected)

__device__ __forceinline__ unsigned short f2bf(float f) {
  unsigned u = __float_as_uint(f);
  unsigned r = 0x7FFFu + ((u >> 16) & 1u);   // RTNE
  return (unsigned short)((u + r) >> 16);
}
__device__ __forceinline__ float bf2f(unsigned short h) {
  return __uint_as_float((unsigned)h << 16);
}

// ---------------- prep: images (coalesced) + workspace zeroing ----------------
// blocks 0-7: w2 chunks; 8-15: wp1 chunks; 16-23: zero stats+hist
__global__ __launch_bounds__(256) void k_prep(
    const float* __restrict__ w2, const float* __restrict__ wp1,
    unsigned short* __restrict__ w2h, unsigned short* __restrict__ w2l,
    unsigned short* __restrict__ p1h, unsigned short* __restrict__ p1l,
    uint4* __restrict__ zero_base)
{
  const int t = threadIdx.x, bx = blockIdx.x;
  if (bx >= 16) {
    const int z = bx - 16;
    const unsigned nz = (256u + NB * NBUCK * 4u) / 16u;  // uint4 count
    uint4 zv = {0u, 0u, 0u, 0u};
    for (unsigned i = z * 256 + t; i < nz; i += 2048) zero_base[i] = zv;
    return;
  }
  __shared__ unsigned short lh[8192], ll[8192];
  const int c = bx & 7;
  const float* src = (bx >= 8) ? wp1 : w2;
  unsigned short* dh = (bx >= 8) ? p1h : w2h;
  unsigned short* dl = (bx >= 8) ? p1l : w2l;
  const int sw = (t >> 1) & 3;
#pragma unroll
  for (int kk = 0; kk < 32; ++kk) {
    float v = src[(c * 32 + kk) * 256 + t];      // coalesced 256-wide
    unsigned short h = f2bf(v);
    int q = kk >> 3, kof = kk & 7;
    int off = t * 32 + ((q ^ sw) << 3) + kof;
    lh[off] = h;
    ll[off] = f2bf(v - bf2f(h));
  }
  __syncthreads();
#pragma unroll
  for (int u = 0; u < 4; ++u) {
    ((uint4*)&dh[c * 8192])[u * 256 + t] = ((const uint4*)lh)[u * 256 + t];
    ((uint4*)&dl[c * 8192])[u * 256 + t] = ((const uint4*)ll)[u * 256 + t];
  }
}

// ---------------- K1: point MLP; B in registers (prefetched), A dbuf in LDS ----------------
__global__ __launch_bounds__(256, 2) void k_mlp(
    const float4* __restrict__ pts4, const float* __restrict__ w1,
    const float* __restrict__ b1,
    const unsigned short* __restrict__ w2h, const unsigned short* __restrict__ w2l,
    const float* __restrict__ b2, const float* __restrict__ wsv,
    const float* __restrict__ bs,
    uint4* __restrict__ pf_u4, float* __restrict__ s_raw, float* stats_f)
{
  __shared__ __align__(16) short a_s[2][4096];   // [buf][hi 2048 | lo 2048] 16 KB
  __shared__ float w1_l[1024];
  __shared__ float b1_l[256];
  __shared__ float pts_l[256];                   // 64 rows x 4

  const int t = threadIdx.x;
  const int m0 = blockIdx.x * 64;
  const int wv = t >> 6, lane = t & 63, g = lane >> 4, c0 = lane & 15;
  const int kq = t & 15, mg = t >> 4;

#pragma unroll
  for (int i = 0; i < 4; ++i) w1_l[i * 256 + t] = w1[i * 256 + t];
  b1_l[t] = b1[t];
  if (t < 64) ((float4*)pts_l)[t] = pts4[m0 + t];

  f32x4 acc[4][4];
#pragma unroll
  for (int i = 0; i < 4; ++i)
#pragma unroll
    for (int j = 0; j < 4; ++j) acc[i][j] = (f32x4){0.f, 0.f, 0.f, 0.f};
  __syncthreads();

  // this thread's 4 point rows, kept in regs
  float4 prow[4];
#pragma unroll
  for (int r = 0; r < 4; ++r) prow[r] = ((const float4*)pts_l)[mg * 4 + r];

  // per-lane B fragment global offsets (frag-order image)
  int boff[4];
#pragma unroll
  for (int nt = 0; nt < 4; ++nt) {
    int n = wv * 64 + nt * 16 + c0;
    boff[nt] = n * 32 + ((g ^ ((n >> 1) & 3)) << 3);
  }

  auto loadB = [&](int cc, bf16x8* bh, bf16x8* bl) {
#pragma unroll
    for (int nt = 0; nt < 4; ++nt) {
      bh[nt] = *(const bf16x8*)&w2h[cc * 8192 + boff[nt]];
      bl[nt] = *(const bf16x8*)&w2l[cc * 8192 + boff[nt]];
    }
  };
  const int qa = kq >> 2, kof = (2 * kq) & 7;
  auto computeA = [&](int cc, int bb) {
    int kg = cc * 32 + 2 * kq;
    float wa0 = w1_l[kg],       wa1 = w1_l[256 + kg];
    float wa2 = w1_l[512 + kg], wa3 = w1_l[768 + kg];
    float wb0 = w1_l[kg + 1],       wb1 = w1_l[256 + kg + 1];
    float wb2 = w1_l[512 + kg + 1], wb3 = w1_l[768 + kg + 1];
    float ba = b1_l[kg], bb_ = b1_l[kg + 1];
    short* ah = &a_s[bb][0];
    short* al = &a_s[bb][2048];
#pragma unroll
    for (int r = 0; r < 4; ++r) {
      int m = mg * 4 + r;
      float4 pv = prow[r];
      float h0 = fmaf(pv.w, wa3, fmaf(pv.z, wa2, fmaf(pv.y, wa1, fmaf(pv.x, wa0, ba))));
      float h1 = fmaf(pv.w, wb3, fmaf(pv.z, wb2, fmaf(pv.y, wb1, fmaf(pv.x, wb0, bb_))));
      h0 = fmaxf(h0, 0.f); h1 = fmaxf(h1, 0.f);
      unsigned short h0h = f2bf(h0), h1h = f2bf(h1);
      unsigned short l0h = f2bf(h0 - bf2f(h0h)), l1h = f2bf(h1 - bf2f(h1h));
      int base = m * 32 + ((qa ^ ((m >> 1) & 3)) << 3) + kof;
      *(unsigned*)&ah[base] = (unsigned)h0h | ((unsigned)h1h << 16);
      *(unsigned*)&al[base] = (unsigned)l0h | ((unsigned)l1h << 16);
    }
  };
  auto mfmaChunk = [&](int cb, const bf16x8* bh, const bf16x8* bl) {
    const short* ah = &a_s[cb][0];
    const short* al = &a_s[cb][2048];
#pragma unroll
    for (int mt = 0; mt < 4; ++mt) {
      int m = mt * 16 + c0;
      int off = m * 32 + ((g ^ ((m >> 1) & 3)) << 3);
      bf16x8 af = *(const bf16x8*)&ah[off];
      bf16x8 alf = *(const bf16x8*)&al[off];
#pragma unroll
      for (int nt = 0; nt < 4; ++nt) {
        acc[mt][nt] = __builtin_amdgcn_mfma_f32_16x16x32_bf16(af, bh[nt], acc[mt][nt], 0, 0, 0);
        acc[mt][nt] = __builtin_amdgcn_mfma_f32_16x16x32_bf16(alf, bh[nt], acc[mt][nt], 0, 0, 0);
        acc[mt][nt] = __builtin_amdgcn_mfma_f32_16x16x32_bf16(af, bl[nt], acc[mt][nt], 0, 0, 0);
      }
    }
  };

  bf16x8 bh0[4], bl0[4], bh1[4], bl1[4];
  loadB(0, bh0, bl0);
  computeA(0, 0);
  __syncthreads();
#pragma unroll
  for (int c = 0; c < 8; ++c) {
    if ((c & 1) == 0) {
      if (c < 7) loadB(c + 1, bh1, bl1);
      mfmaChunk(0, bh0, bl0);
    } else {
      if (c < 7) loadB(c + 1, bh0, bl0);
      mfmaChunk(1, bh1, bl1);
    }
    if (c < 7) computeA(c + 1, (c + 1) & 1);
    __syncthreads();
  }

  // ---- epilogue: relu+b2 -> pf bf16 (2 passes of 32 rows via LDS), s row-sums ----
  unsigned short* pstage = (unsigned short*)&a_s[0][0];  // 16 KB overlay
  float* spart = (float*)w1_l;                           // 1 KB overlay
  float wsr[4], b2v[4];
#pragma unroll
  for (int nt = 0; nt < 4; ++nt) {
    int col = wv * 64 + nt * 16 + c0;
    wsr[nt] = wsv[col]; b2v[nt] = b2[col];
  }
  for (int p = 0; p < 2; ++p) {
#pragma unroll
    for (int mi = 0; mi < 2; ++mi) {
      int mt = p * 2 + mi;
      float srow[4] = {0.f, 0.f, 0.f, 0.f};
#pragma unroll
      for (int nt = 0; nt < 4; ++nt) {
        f32x4 z = acc[mt][nt];
#pragma unroll
        for (int r = 0; r < 4; ++r) {
          float pp = fmaxf(z[r] + b2v[nt], 0.f);
          srow[r] = fmaf(pp, wsr[nt], srow[r]);
          pstage[(mi * 16 + g * 4 + r) * 256 + wv * 64 + nt * 16 + c0] = f2bf(pp);
        }
      }
#pragma unroll
      for (int r = 0; r < 4; ++r) {
#pragma unroll
        for (int off = 1; off <= 8; off <<= 1) srow[r] += __shfl_xor(srow[r], off);
        if (c0 == 0) spart[(mt * 16 + g * 4 + r) * 4 + wv] = srow[r];
      }
    }
    __syncthreads();
#pragma unroll
    for (int u = 0; u < 4; ++u) {
      int jj = u * 256 + t, row = jj >> 5, c4 = jj & 31;
      pf_u4[(size_t)(m0 + p * 32 + row) * 32 + c4] = ((const uint4*)pstage)[jj];
    }
    __syncthreads();
  }
  if (t < 64) {
    float s = bs[0] + spart[t * 4] + spart[t * 4 + 1] + spart[t * 4 + 2] + spart[t * 4 + 3];
    s_raw[m0 + t] = s;
    float s2 = s * s;
#pragma unroll
    for (int off = 32; off >= 1; off >>= 1) {
      s += __shfl_down(s, off);
      s2 += __shfl_down(s2, off);
    }
    if (t == 0) {
      atomicAdd(&stats_f[SI_SUMS], s);
      atomicAdd(&stats_f[SI_SUMS2], s2);
    }
  }
}

// ---------------- K2: scores (BN fused) + fine histogram + EALL ----------------
__global__ __launch_bounds__(256) void k_scores(
    const float* __restrict__ s_raw, const float* stats_f,
    const float* __restrict__ gamma, const float* __restrict__ beta,
    float* __restrict__ scores, unsigned* __restrict__ hist, float* stats_fo)
{
  int i = blockIdx.x * 256 + threadIdx.x;
  int batch = i >> 14;
  float mu = stats_f[SI_SUMS] * (1.f / 65536.f);
  float ex2 = stats_f[SI_SUMS2] * (1.f / 65536.f);
  float istd = 1.f / sqrtf(ex2 - mu * mu + 1e-5f);
  float sc = fmaxf((s_raw[i] - mu) * istd * gamma[0] + beta[0], 0.f);
  scores[i] = sc;
  unsigned bucket = __float_as_uint(sc) >> 17;
  if (bucket > NBUCK - 1u) bucket = NBUCK - 1u;
  if (bucket >= 1u) atomicAdd(&hist[batch * NBUCK + bucket], 1u);
  float e = expf((sc - 5.f) * 10.f);
#pragma unroll
  for (int off = 32; off >= 1; off >>= 1) e += __shfl_down(e, off);
  if ((threadIdx.x & 63) == 0) atomicAdd(&stats_fo[SI_EALL + batch], e);
}

// ---------------- K3: fused suffix-scan + scatter (per batch block) ----------------
__global__ __launch_bounds__(1024) void k_sel(
    const float* __restrict__ scores, const unsigned* __restrict__ hist,
    unsigned* __restrict__ suf, unsigned* stats_u, ull* __restrict__ cand)
{
  __shared__ unsigned lh[NBUCK];      // 64 KB
  __shared__ unsigned wsum[16], wsuf[16];
  __shared__ unsigned sb_cut, sb_tot;
  const int batch = blockIdx.x, t = threadIdx.x;
  const int base = batch * NBUCK;
  const int lane = t & 63, w = t >> 6;
  if (t == 0) { sb_cut = 0u; sb_tot = PPB; }
#pragma unroll
  for (int j = 0; j < 16; ++j) lh[j * 1024 + t] = hist[base + j * 1024 + t];
  __syncthreads();
  unsigned hl[16]; unsigned ct = 0;
#pragma unroll
  for (int i = 0; i < 16; ++i) { hl[i] = lh[t * 16 + i]; ct += hl[i]; }
  unsigned x = ct;
#pragma unroll
  for (int off = 1; off <= 32; off <<= 1) {
    unsigned v = __shfl_down(x, off);
    if (lane + off < 64) x += v;
  }
  if (lane == 0) wsum[w] = x;
  __syncthreads();
  if (t < 16) {
    unsigned s = 0;
    for (int j = t + 1; j < 16; ++j) s += wsum[j];
    wsuf[t] = s;
  }
  __syncthreads();
  unsigned run = wsuf[w] + (x - ct);
  for (int i = 15; i >= 0; --i) {
    int b = t * 16 + i;
    unsigned h = hl[i];
    lh[b] = run;
    if (b >= 1 && run < TOPK && run + h >= TOPK) { sb_cut = (unsigned)b; sb_tot = run + h; }
    run += h;
  }
  __syncthreads();
  // write pristine suffix to global (k_rank needs it), then scatter using LDS cursors
#pragma unroll
  for (int j = 0; j < 16; ++j) suf[base + j * 1024 + t] = lh[j * 1024 + t];
  if (t == 0) stats_u[SI_CNT0 + batch] = sb_tot;
  __syncthreads();
  const unsigned cut = sb_cut;
  for (int i = t; i < PPB; i += 1024) {
    int pt = batch * PPB + i;
    unsigned bits = __float_as_uint(scores[pt]);
    unsigned bucket = bits >> 17;
    if (bucket > NBUCK - 1u) bucket = NBUCK - 1u;
    if (bucket >= cut) {
      unsigned pos = atomicAdd(&lh[bucket], 1u);
      cand[batch * PPB + pos] = ((ull)bits << 32) | (ull)(~(unsigned)pt);
    }
  }
}

// ---------------- K4: rank within segment -> flat_idx + ESEL ----------------
__global__ __launch_bounds__(1024) void k_rank(
    const ull* __restrict__ cand, const unsigned* __restrict__ suf,
    const unsigned* stats_u, float* stats_f, int* __restrict__ flat_idx)
{
  int tid = blockIdx.x * 1024 + threadIdx.x;
  int batch = tid >> 14;
  int pos = tid & 16383;
  unsigned tot = stats_u[SI_CNT0 + batch];
  float esel = 0.f;
  if ((unsigned)pos < tot) {
    ull key = cand[batch * PPB + pos];
    unsigned bits = (unsigned)(key >> 32);
    unsigned bucket = bits >> 17;
    unsigned s0 = suf[batch * NBUCK + bucket];
    unsigned s1 = (bucket >= 1u) ? suf[batch * NBUCK + bucket - 1] : tot;
    unsigned rank = s0;
    const ull* seg = &cand[batch * PPB];
    for (unsigned p = s0; p < s1; ++p) rank += (seg[p] > key);
    if (rank < TOPK) {
      flat_idx[batch * TOPK + rank] = (int)(~(unsigned)key);
      esel = expf((__uint_as_float(bits) - 5.f) * 10.f);
    }
  }
#pragma unroll
  for (int off = 32; off >= 1; off >>= 1) esel += __shfl_down(esel, off);
  if ((threadIdx.x & 63) == 0) atomicAdd(&stats_f[SI_ESEL + batch], esel);
}

// ---------------- K5: processor MLP; B in registers (2-chain), A gather dbuf ----------------
__global__ __launch_bounds__(256, 2) void k_proc(
    const uint4* __restrict__ pf_u4, const float* __restrict__ scores,
    const float* stats_f, const int* __restrict__ flat_idx,
    const unsigned short* __restrict__ p1h, const unsigned short* __restrict__ p1l,
    const float* __restrict__ bp1,
    const float4* __restrict__ wp2_4, const float* __restrict__ bp2,
    float4* __restrict__ out4)
{
  __shared__ __align__(16) short a_s[2][2048];   // 8 KB (A dbuf)
  __shared__ int idx_t[64];
  __shared__ float sw_t[64];
  __shared__ float opart[4 * 64 * 4];
  const int t = threadIdx.x;
  const int m0 = blockIdx.x * 64;
  const int b = m0 >> 12;
  const int wv = t >> 6, lane = t & 63, g = lane >> 4, c0 = lane & 15;
  const int mq = t >> 2, qa = t & 3;

  if (t < 64) {
    int idx = flat_idx[m0 + t];
    float Z = stats_f[SI_EALL] + stats_f[SI_EALL + 1] +
              stats_f[SI_EALL + 2] + stats_f[SI_EALL + 3];
    float E = expf((scores[idx] - 5.f) * 10.f);
    idx_t[t] = idx;
    sw_t[t] = E / (stats_f[SI_ESEL + b] + 1e-8f * Z);
  }
  f32x4 acc[4][4];
#pragma unroll
  for (int i = 0; i < 4; ++i)
#pragma unroll
    for (int j = 0; j < 4; ++j) acc[i][j] = (f32x4){0.f, 0.f, 0.f, 0.f};
  __syncthreads();

  const size_t arow = (size_t)idx_t[mq] * 32;
  const int awr = mq * 32 + ((qa ^ ((mq >> 1) & 3)) << 3);

  int boff[4];
#pragma unroll
  for (int nt = 0; nt < 4; ++nt) {
    int n = wv * 64 + nt * 16 + c0;
    boff[nt] = n * 32 + ((g ^ ((n >> 1) & 3)) << 3);
  }
  auto loadB = [&](int cc, bf16x8* bh, bf16x8* bl) {
#pragma unroll
    for (int nt = 0; nt < 4; ++nt) {
      bh[nt] = *(const bf16x8*)&p1h[cc * 8192 + boff[nt]];
      bl[nt] = *(const bf16x8*)&p1l[cc * 8192 + boff[nt]];
    }
  };
  auto gatherA = [&](int cc, int bb) {
    uint4 v = pf_u4[arow + cc * 4 + qa];
    *(uint4*)&a_s[bb][awr] = v;
  };
  auto mfmaChunk = [&](int cb, const bf16x8* bh, const bf16x8* bl) {
#pragma unroll
    for (int mt = 0; mt < 4; ++mt) {
      int m = mt * 16 + c0;
      bf16x8 af = *(const bf16x8*)&a_s[cb][m * 32 + ((g ^ ((m >> 1) & 3)) << 3)];
#pragma unroll
      for (int nt = 0; nt < 4; ++nt) {
        acc[mt][nt] = __builtin_amdgcn_mfma_f32_16x16x32_bf16(af, bh[nt], acc[mt][nt], 0, 0, 0);
        acc[mt][nt] = __builtin_amdgcn_mfma_f32_16x16x32_bf16(af, bl[nt], acc[mt][nt], 0, 0, 0);
      }
    }
  };

  bf16x8 bh0[4], bl0[4], bh1[4], bl1[4];
  loadB(0, bh0, bl0);
  gatherA(0, 0);
  __syncthreads();
#pragma unroll
  for (int c = 0; c < 8; ++c) {
    if ((c & 1) == 0) {
      if (c < 7) loadB(c + 1, bh1, bl1);
      mfmaChunk(0, bh0, bl0);
    } else {
      if (c < 7) loadB(c + 1, bh0, bl0);
      mfmaChunk(1, bh1, bl1);
    }
    if (c < 7) gatherA(c + 1, (c + 1) & 1);
    __syncthreads();
  }

  float4 wq[4]; float bp1v[4];
#pragma unroll
  for (int nt = 0; nt < 4; ++nt) {
    int n = wv * 64 + nt * 16 + c0;
    wq[nt] = wp2_4[n]; bp1v[nt] = bp1[n];
  }
#pragma unroll
  for (int mt = 0; mt < 4; ++mt) {
#pragma unroll
    for (int r = 0; r < 4; ++r) {
      float4 o = {0.f, 0.f, 0.f, 0.f};
#pragma unroll
      for (int nt = 0; nt < 4; ++nt) {
        float y = fmaxf(acc[mt][nt][r] + bp1v[nt], 0.f);
        o.x = fmaf(y, wq[nt].x, o.x); o.y = fmaf(y, wq[nt].y, o.y);
        o.z = fmaf(y, wq[nt].z, o.z); o.w = fmaf(y, wq[nt].w, o.w);
      }
#pragma unroll
      for (int off = 1; off <= 8; off <<= 1) {
        o.x += __shfl_xor(o.x, off); o.y += __shfl_xor(o.y, off);
        o.z += __shfl_xor(o.z, off); o.w += __shfl_xor(o.w, off);
      }
      if (c0 == 0) *(float4*)&opart[(wv * 64 + mt * 16 + g * 4 + r) * 4] = o;
    }
  }
  __syncthreads();
  if (t < 64) {
    float4 bp2v = *(const float4*)bp2;
    float4 s0 = *(float4*)&opart[t * 4];
    float4 s1 = *(float4*)&opart[(64 + t) * 4];
    float4 s2 = *(float4*)&opart[(128 + t) * 4];
    float4 s3 = *(float4*)&opart[(192 + t) * 4];
    float sw = sw_t[t];
    float4 r;
    r.x = fmaf(s0.x + s1.x + s2.x + s3.x, sw, bp2v.x);
    r.y = fmaf(s0.y + s1.y + s2.y + s3.y, sw, bp2v.y);
    r.z = fmaf(s0.z + s1.z + s2.z + s3.z, sw, bp2v.z);
    r.w = fmaf(s0.w + s1.w + s2.w + s3.w, sw, bp2v.w);
    out4[m0 + t] = r;
  }
}

extern "C" void kernel_launch(void* const* d_in, const int* in_sizes, int n_in,
                              void* d_out, int out_size, void* d_ws, size_t ws_size,
                              hipStream_t stream) {
  const float* pts   = (const float*)d_in[0];
  const float* w1    = (const float*)d_in[1];
  const float* b1    = (const float*)d_in[2];
  const float* w2    = (const float*)d_in[3];
  const float* b2    = (const float*)d_in[4];
  const float* wsv   = (const float*)d_in[5];
  const float* bs    = (const float*)d_in[6];
  const float* gamma = (const float*)d_in[7];
  const float* beta  = (const float*)d_in[8];
  const float* wp1   = (const float*)d_in[9];
  const float* bp1   = (const float*)d_in[10];
  const float* wp2   = (const float*)d_in[11];
  const float* bp2   = (const float*)d_in[12];

  char* wsb = (char*)d_ws;
  uint4*    pf      = (uint4*)(wsb + PF_OFF);
  float*    s_raw   = (float*)(wsb + SRAW_OFF);
  float*    scores  = (float*)(wsb + SC_OFF);
  float*    stats_f = (float*)(wsb + ST_OFF);
  unsigned* stats_u = (unsigned*)(wsb + ST_OFF);
  unsigned* hist    = (unsigned*)(wsb + HIST_OFF);
  unsigned* suf     = (unsigned*)(wsb + SUF_OFF);
  ull*      cand    = (ull*)(wsb + CAND_OFF);
  int*      flat_i  = (int*)(wsb + FIDX_OFF);
  unsigned short* w2h = (unsigned short*)(wsb + W2SH_OFF);
  unsigned short* w2l = (unsigned short*)(wsb + W2SL_OFF);
  unsigned short* p1h = (unsigned short*)(wsb + WP1H_OFF);
  unsigned short* p1l = (unsigned short*)(wsb + WP1L_OFF);

  hipLaunchKernelGGL(k_prep, dim3(24), dim3(256), 0, stream,
                     w2, wp1, w2h, w2l, p1h, p1l, (uint4*)(wsb + ST_OFF));
  hipLaunchKernelGGL(k_mlp, dim3(1024), dim3(256), 0, stream,
                     (const float4*)pts, w1, b1, w2h, w2l, b2, wsv, bs,
                     pf, s_raw, stats_f);
  hipLaunchKernelGGL(k_scores, dim3(256), dim3(256), 0, stream,
                     s_raw, stats_f, gamma, beta, scores, hist, stats_f);
  hipLaunchKernelGGL(k_sel, dim3(NB), dim3(1024), 0, stream,
                     scores, hist, suf, stats_u, cand);
  hipLaunchKernelGGL(k_rank, dim3(64), dim3(1024), 0, stream,
                     cand, suf, stats_u, stats_f, flat_i);
  hipLaunchKernelGGL(k_proc, dim3(256), dim3(256), 0, stream,
                     pf, scores, stats_f, flat_i, p1h, p1l, bp1,
                     (const float4*)wp2, bp2, (float4*)d_out);
}